// Round 4
// baseline (896.217 us; speedup 1.0000x reference)
//
#include <hip/hip_runtime.h>

typedef __attribute__((ext_vector_type(8))) __bf16 bf16x8;
typedef __attribute__((ext_vector_type(4))) float f32x4;
typedef __attribute__((ext_vector_type(4))) unsigned int u32x4;

__device__ __forceinline__ float bf2f(unsigned short u){
    unsigned int x = ((unsigned int)u) << 16;
    return __builtin_bit_cast(float, x);
}
__device__ __forceinline__ unsigned short f2bf(float f){
    unsigned int x = __builtin_bit_cast(unsigned int, f);
    x += 0x7FFFu + ((x >> 16) & 1u);
    return (unsigned short)(x >> 16);
}
__device__ __forceinline__ unsigned int pk2(float a, float b){
    return (unsigned int)f2bf(a) | ((unsigned int)f2bf(b) << 16);
}
__device__ __forceinline__ bf16x8 ldfrag(const unsigned short* p){
    u32x4 v = *reinterpret_cast<const u32x4*>(p);
    return __builtin_bit_cast(bf16x8, v);
}
// fp32 global -> bf16 fragment (8 elements)
__device__ __forceinline__ bf16x8 ldf32(const float* p){
    f32x4 a = *reinterpret_cast<const f32x4*>(p);
    f32x4 b = *reinterpret_cast<const f32x4*>(p + 4);
    u32x4 r;
    r[0] = pk2(a[0], a[1]); r[1] = pk2(a[2], a[3]);
    r[2] = pk2(b[0], b[1]); r[3] = pk2(b[2], b[3]);
    return __builtin_bit_cast(bf16x8, r);
}
__device__ __forceinline__ f32x4 mfma_bf16(bf16x8 a, bf16x8 b, f32x4 c){
    return __builtin_amdgcn_mfma_f32_16x16x32_bf16(a, b, c, 0, 0, 0);
}

#define WINELEMS 1568           // 49*32 per (window,head)
#define NWIN 24576              // 128*3*64

// ---------------- Kernel 1: QKV projection + shift + window-partition scatter ----------
__global__ __launch_bounds__(256) void k_qkv(const float* __restrict__ x,
                                             const float* __restrict__ w1,
                                             const float* __restrict__ b1,
                                             unsigned short* __restrict__ qb,
                                             unsigned short* __restrict__ kb,
                                             unsigned short* __restrict__ vb)
{
    __shared__ float lds[64 * 146];
    const int tid = threadIdx.x;
    const int wave = tid >> 6, lane = tid & 63;
    const int l15 = lane & 15, qd = lane >> 4;
    const int m0 = blockIdx.x * 64 + wave * 16;

    const float* xr = x + (size_t)(m0 + l15) * 96 + qd * 8;
    bf16x8 a0 = ldf32(xr);
    bf16x8 a1 = ldf32(xr + 32);
    bf16x8 a2 = ldf32(xr + 64);

    f32x4 acc[18];
#pragma unroll
    for (int g = 0; g < 18; ++g){
        const float* wr = w1 + (size_t)(g * 16 + l15) * 96 + qd * 8;
        f32x4 a = {0.f, 0.f, 0.f, 0.f};
        a = mfma_bf16(a0, ldf32(wr), a);
        a = mfma_bf16(a1, ldf32(wr + 32), a);
        a = mfma_bf16(a2, ldf32(wr + 64), a);
        acc[g] = a;
    }

#pragma unroll
    for (int ph = 0; ph < 2; ++ph){
#pragma unroll
        for (int nt = 0; nt < 9; ++nt){
            int g = ph * 9 + nt;
            float bias = b1[g * 16 + l15];
#pragma unroll
            for (int r = 0; r < 4; ++r)
                lds[(wave * 16 + qd * 4 + r) * 146 + nt * 16 + l15] = acc[g][r] + bias;
        }
        __syncthreads();
        // scatter: chunk = (row 0..63, sel 0..2, c 0..2) -> 16 eh values
        for (int chunk = tid; chunk < 576; chunk += 256){
            int row = chunk / 9; int t9 = chunk - row * 9;
            int sel = t9 / 3, c = t9 - sel * 3;
            int e0 = ph * 48 + sel * 16;
            int H = e0 >> 5, eh0 = e0 & 31;
            int m = blockIdx.x * 64 + row;
            int b = m / 3136, p = m - b * 3136;
            int h = p / 56, w = p - h * 56;
            int hs = h + 52; if (hs >= 56) hs -= 56;    // window coord = orig - 4 (roll -4)
            int ws2 = w + 52; if (ws2 >= 56) ws2 -= 56;
            int wy = hs / 7, iy = hs - wy * 7;
            int wx = ws2 / 7, ix = ws2 - wx * 7;
            int pos = iy * 7 + ix;
            unsigned short* dstb = (c == 0) ? qb : ((c == 1) ? kb : vb);
            unsigned short* dst = dstb + ((size_t)((b * 3 + H) * 64 + wy * 8 + wx)) * WINELEMS
                                + pos * 32 + eh0;
            const float* src = lds + row * 146 + (e0 * 3 + c - ph * 144);
            u32x4 pk0, pk1;
#pragma unroll
            for (int j = 0; j < 4; ++j){
                pk0[j] = pk2(src[3 * (2 * j)],     src[3 * (2 * j + 1)]);
                pk1[j] = pk2(src[3 * (8 + 2 * j)], src[3 * (8 + 2 * j + 1)]);
            }
            *reinterpret_cast<u32x4*>(dst)     = pk0;
            *reinterpret_cast<u32x4*>(dst + 8) = pk1;
        }
        __syncthreads();
    }
}

// ---------------- Kernel 2: windowed attention (one wave per (b,H,window)) ----------
__global__ __launch_bounds__(64) void k_attn(const unsigned short* __restrict__ qb,
                                             const unsigned short* __restrict__ kb,
                                             const unsigned short* __restrict__ vb,
                                             unsigned short* __restrict__ ob)
{
    __shared__ unsigned short Vt[32 * 72];   // [eh][key], stride 72
    __shared__ unsigned short P[64 * 72];    // [qrow][key], stride 72
    const int lane = threadIdx.x;
    const int win = blockIdx.x;
    const int wx = win & 7, wy = (win >> 3) & 7;
    const int H = (win >> 6) % 3, b = win / 192;
    const unsigned short* qw = qb + (size_t)win * WINELEMS;
    const unsigned short* kw = kb + (size_t)win * WINELEMS;
    const unsigned short* vw = vb + (size_t)win * WINELEMS;

    // stage V transposed (coalesced read, scatter LDS write)
    for (int i = lane; i < 1568; i += 64){
        int key = i >> 5, eh = i & 31;
        Vt[eh * 72 + key] = vw[i];
    }
    // zero pad keys 49..63
    for (int i = lane; i < 32 * 15; i += 64){
        int eh = i / 15, key = 49 + (i - eh * 15);
        Vt[eh * 72 + key] = 0;
    }

    const int l15 = lane & 15, qd = lane >> 4;

    bf16x8 aQ[4];
#pragma unroll
    for (int tm = 0; tm < 4; ++tm) aQ[tm] = ldfrag(qw + (tm * 16 + l15) * 32 + qd * 8);

    f32x4 S[4][4];
#pragma unroll
    for (int tn = 0; tn < 4; ++tn){
        bf16x8 bK = ldfrag(kw + (tn * 16 + l15) * 32 + qd * 8);
#pragma unroll
        for (int tm = 0; tm < 4; ++tm){
            f32x4 z = {0.f, 0.f, 0.f, 0.f};
            S[tm][tn] = mfma_bf16(aQ[tm], bK, z);
        }
    }

    // masked softmax in C-layout registers; each row lives in one 16-lane group
    const bool rowm = (wy == 7), colm = (wx == 7);
    const float scale = 0.17677669529663687f;   // 1/sqrt(32)
    const float NEGINF = -__builtin_inff();
    float rs[4][4];
#pragma unroll
    for (int tm = 0; tm < 4; ++tm){
#pragma unroll
        for (int r = 0; r < 4; ++r){
            int row = tm * 16 + qd * 4 + r;
            float mx = NEGINF;
#pragma unroll
            for (int tn = 0; tn < 4; ++tn){
                int col = tn * 16 + l15;
                float v = S[tm][tn][r] * scale;
                bool blocked = (col >= 49)
                    || (rowm && ((row >= 28) != (col >= 28)))
                    || (colm && (((row % 7) >= 4) != ((col % 7) >= 4)));
                v = blocked ? NEGINF : v;
                S[tm][tn][r] = v;
                mx = fmaxf(mx, v);
            }
#pragma unroll
            for (int s = 1; s < 16; s <<= 1) mx = fmaxf(mx, __shfl_xor(mx, s, 64));
            float sum = 0.f;
#pragma unroll
            for (int tn = 0; tn < 4; ++tn){
                float e = exp2f((S[tm][tn][r] - mx) * 1.4426950408889634f);
                S[tm][tn][r] = e;
                sum += e;
            }
#pragma unroll
            for (int s = 1; s < 16; s <<= 1) sum += __shfl_xor(sum, s, 64);
            rs[tm][r] = sum;
#pragma unroll
            for (int tn = 0; tn < 4; ++tn)
                P[row * 72 + tn * 16 + l15] = f2bf(S[tm][tn][r]);
        }
    }

    __syncthreads();   // Vt staging + P writes visible

    // O = P * V   (K = 64 keys, 2 k-steps; N = 32 eh, 2 n-tiles)
    f32x4 O[4][2];
#pragma unroll
    for (int tm = 0; tm < 4; ++tm)
#pragma unroll
        for (int tn = 0; tn < 2; ++tn) O[tm][tn] = (f32x4){0.f, 0.f, 0.f, 0.f};

#pragma unroll
    for (int kt = 0; kt < 2; ++kt){
        bf16x8 aP[4];
#pragma unroll
        for (int tm = 0; tm < 4; ++tm)
            aP[tm] = ldfrag((const unsigned short*)P + (tm * 16 + l15) * 72 + kt * 32 + qd * 8);
#pragma unroll
        for (int tn = 0; tn < 2; ++tn){
            bf16x8 bV = ldfrag((const unsigned short*)Vt + (tn * 16 + l15) * 72 + kt * 32 + qd * 8);
#pragma unroll
            for (int tm = 0; tm < 4; ++tm) O[tm][tn] = mfma_bf16(aP[tm], bV, O[tm][tn]);
        }
    }

    // epilogue: normalize, undo window partition + roll(+3), scatter bf16
#pragma unroll
    for (int tm = 0; tm < 4; ++tm){
#pragma unroll
        for (int r = 0; r < 4; ++r){
            int row = tm * 16 + qd * 4 + r;
            if (row < 49){
                float inv = 1.f / rs[tm][r];
                int iy = row / 7, ix = row - iy * 7;
                int h = wy * 7 + iy + 3; if (h >= 56) h -= 56;   // roll +3
                int w = wx * 7 + ix + 3; if (w >= 56) w -= 56;
                size_t base = ((size_t)b * 3136 + h * 56 + w) * 96 + H * 32;
#pragma unroll
                for (int tn = 0; tn < 2; ++tn)
                    ob[base + tn * 16 + l15] = f2bf(O[tm][tn][r] * inv);
            }
        }
    }
}

// ---------------- Kernel 3: output projection -> fp32 out ----------
__global__ __launch_bounds__(256) void k_proj(const unsigned short* __restrict__ ob,
                                              const float* __restrict__ w2,
                                              const float* __restrict__ b2,
                                              float* __restrict__ out)
{
    __shared__ float lds[64 * 100];
    const int tid = threadIdx.x;
    const int wave = tid >> 6, lane = tid & 63;
    const int l15 = lane & 15, qd = lane >> 4;
    const int m0 = blockIdx.x * 64 + wave * 16;

    const unsigned short* xr = ob + (size_t)(m0 + l15) * 96 + qd * 8;
    bf16x8 a0 = ldfrag(xr);
    bf16x8 a1 = ldfrag(xr + 32);
    bf16x8 a2 = ldfrag(xr + 64);

#pragma unroll
    for (int g = 0; g < 6; ++g){
        const float* wr = w2 + (size_t)(g * 16 + l15) * 96 + qd * 8;
        f32x4 a = {0.f, 0.f, 0.f, 0.f};
        a = mfma_bf16(a0, ldf32(wr), a);
        a = mfma_bf16(a1, ldf32(wr + 32), a);
        a = mfma_bf16(a2, ldf32(wr + 64), a);
        float bias = b2[g * 16 + l15];
#pragma unroll
        for (int r = 0; r < 4; ++r)
            lds[(wave * 16 + qd * 4 + r) * 100 + g * 16 + l15] = a[r] + bias;
    }
    __syncthreads();

    // 64 rows x 96 cols fp32 out; thread t: row = t/4, 24-col segment = t%4
    int row = tid >> 2, seg = tid & 3;
    const float* src = lds + row * 100 + seg * 24;
    float* dst = out + ((size_t)blockIdx.x * 64 + row) * 96 + seg * 24;
#pragma unroll
    for (int v = 0; v < 6; ++v){
        f32x4 t4;
#pragma unroll
        for (int j = 0; j < 4; ++j) t4[j] = src[v * 4 + j];
        *reinterpret_cast<f32x4*>(dst + v * 4) = t4;
    }
}

extern "C" void kernel_launch(void* const* d_in, const int* in_sizes, int n_in,
                              void* d_out, int out_size, void* d_ws, size_t ws_size,
                              hipStream_t stream)
{
    const float* x  = (const float*)d_in[0];
    const float* w1 = (const float*)d_in[1];
    const float* b1 = (const float*)d_in[2];
    const float* w2 = (const float*)d_in[3];
    const float* b2 = (const float*)d_in[4];
    float* out = (float*)d_out;

    unsigned short* qb = (unsigned short*)d_ws;
    unsigned short* kb = qb + (size_t)NWIN * WINELEMS;
    unsigned short* vb = kb + (size_t)NWIN * WINELEMS;
    unsigned short* ob = vb + (size_t)NWIN * WINELEMS;

    hipLaunchKernelGGL(k_qkv,  dim3(6272),  dim3(256), 0, stream, x, w1, b1, qb, kb, vb);
    hipLaunchKernelGGL(k_attn, dim3(24576), dim3(64),  0, stream, qb, kb, vb, ob);
    hipLaunchKernelGGL(k_proj, dim3(6272),  dim3(256), 0, stream, ob, w2, b2, out);
}